// Round 3
// baseline (313.117 us; speedup 1.0000x reference)
//
#include <hip/hip_runtime.h>

typedef __attribute__((ext_vector_type(8))) short short8;
typedef __attribute__((ext_vector_type(4))) float f32x4;
typedef __attribute__((ext_vector_type(16))) float f32x16;

#define DEVFN __device__ __forceinline__

DEVFN unsigned short f2bf(float f) {
  unsigned int u = __builtin_bit_cast(unsigned int, f);
  u += 0x7FFFu + ((u >> 16) & 1u);   // RNE
  return (unsigned short)(u >> 16);
}
DEVFN float bf2f(unsigned int u) { return __builtin_bit_cast(float, u << 16); }

DEVFN unsigned int cvtpk_bf16(float lo, float hi) {
  unsigned int d;
  asm("v_cvt_pk_bf16_f32 %0, %1, %2" : "=v"(d) : "v"(lo), "v"(hi));
  return d;
}
DEVFN void plswap32(unsigned int& a, unsigned int& b) {
  asm("v_permlane32_swap_b32 %0, %1" : "+v"(a), "+v"(b));
}
DEVFN float bcast32(float v, int srclane) {
  int r = __builtin_amdgcn_ds_bpermute(srclane * 4, __builtin_bit_cast(int, v));
  return __builtin_bit_cast(float, r);
}

// ---------------- prep kernels ----------------

// cos/sin tables: [2048 pos][32 freq]
__global__ __launch_bounds__(256) void mk_tables(float* __restrict__ cost, float* __restrict__ sint) {
  int gid = blockIdx.x * 256 + threadIdx.x;   // 65536
  int pos = gid >> 5, i = gid & 31;
  float theta = powf(10000.0f, -(float)(2 * i) / 64.0f);
  float ang = (float)pos * theta;
  cost[gid] = cosf(ang);
  sint[gid] = sinf(ang);
}

__global__ __launch_bounds__(256) void bias_cat_k(const float* __restrict__ bq, const float* __restrict__ bk,
                                                  const float* __restrict__ bv, float* __restrict__ out) {
  int i = blockIdx.x * 256 + threadIdx.x;  // 3072
  float v;
  if (i < 2048) v = bq[i];
  else if (i < 2560) v = bk[i - 2048];
  else v = bv[i - 2560];
  out[i] = v;
}

__global__ __launch_bounds__(256) void convx(const float* __restrict__ x, unsigned short* __restrict__ xb) {
  int gid = blockIdx.x * 256 + threadIdx.x;   // 1048576 threads, 8 f32 each
  const float4* xv = (const float4*)x;
  float4 a = xv[(size_t)gid * 2], b = xv[(size_t)gid * 2 + 1];
  short8 u;
  u[0] = (short)f2bf(a.x); u[1] = (short)f2bf(a.y); u[2] = (short)f2bf(a.z); u[3] = (short)f2bf(a.w);
  u[4] = (short)f2bf(b.x); u[5] = (short)f2bf(b.y); u[6] = (short)f2bf(b.z); u[7] = (short)f2bf(b.w);
  *(short8*)(xb + (size_t)gid * 8) = u;
}

// W [2048][ncols] f32 -> Wt [ncols][2048] bf16 (Wt pre-offset by caller)
__global__ __launch_bounds__(256) void transw(const float* __restrict__ W, unsigned short* __restrict__ Wt, int ncols) {
  __shared__ float lds[32][33];
  int n0 = blockIdx.x * 32, k0 = blockIdx.y * 32;
  int tx = threadIdx.x & 31, ty = threadIdx.x >> 5;
  #pragma unroll
  for (int i = 0; i < 4; i++) {
    int kr = ty + i * 8;
    lds[kr][tx] = W[(size_t)(k0 + kr) * ncols + n0 + tx];
  }
  __syncthreads();
  #pragma unroll
  for (int i = 0; i < 4; i++) {
    int nr = ty + i * 8;
    Wt[(size_t)(n0 + nr) * 2048 + k0 + tx] = f2bf(lds[tx][nr]);
  }
}

// ---------------- RoPE + scatter ----------------
template<int NH>
__global__ __launch_bounds__(256) void rope_scatter(const unsigned short* __restrict__ QKV,
    const float* __restrict__ cost, const float* __restrict__ sint, const int* __restrict__ spp,
    unsigned short* __restrict__ dst, int colOff, float scale) {
  constexpr int LOG2NH = (NH == 16) ? 4 : 2;
  int gid = blockIdx.x * 256 + threadIdx.x;
  int j = gid & 63;
  int h = (gid >> 6) & (NH - 1);
  int m = gid >> (6 + LOG2NH);
  int t = m & 2047;
  const unsigned short* src = QKV + (size_t)m * 3072 + colOff + h * 128 + 2 * j;
  unsigned int pair = *(const unsigned int*)src;
  float xv = bf2f(pair & 0xFFFFu), yv = bf2f(pair >> 16);
  float rx, ry;
  if (j < 32) {
    int pos = (spp[0] + t) & 2047;
    float c = cost[pos * 32 + j], s = sint[pos * 32 + j];
    rx = xv * c - yv * s;
    ry = xv * s + yv * c;
  } else { rx = xv; ry = yv; }
  rx *= scale; ry *= scale;
  size_t drow = ((size_t)((m >> 11) * NH + h)) * 2048 + t;
  unsigned int outp = (unsigned int)f2bf(rx) | ((unsigned int)f2bf(ry) << 16);
  *(unsigned int*)(dst + drow * 128 + 2 * j) = outp;
}

// ---------------- V transpose: QKV[.,2560+kh*128+d] -> Vt[b][kh][d][t] ----------------
__global__ __launch_bounds__(256) void vtrans(const unsigned short* __restrict__ QKV, unsigned short* __restrict__ Vt) {
  __shared__ __align__(16) unsigned short lds[64 * 128];  // swizzled [t][d]
  int tid = threadIdx.x;
  int t0 = blockIdx.x * 64;
  int bk = blockIdx.y;         // b*4 + kh
  const unsigned short* src = QKV + (size_t)(bk >> 2) * 2048 * 3072 + 2560 + (bk & 3) * 128;
  #pragma unroll
  for (int c = 0; c < 4; c++) {
    int idx = c * 256 + tid;
    int tr = idx >> 4, dc = idx & 15;
    short8 v = *(const short8*)(src + (size_t)(t0 + tr) * 3072 + dc * 8);
    *(short8*)((char*)lds + tr * 256 + 16 * (dc ^ (tr >> 3))) = v;
  }
  __syncthreads();
  unsigned short* dstb = Vt + (size_t)bk * 128 * 2048;
  #pragma unroll
  for (int c2 = 0; c2 < 4; c2++) {
    int idx2 = c2 * 256 + tid;
    int tc = idx2 & 7, d = idx2 >> 3;
    short8 u;
    #pragma unroll
    for (int e = 0; e < 8; e++) {
      int t = 8 * tc + e;
      u[e] = *(const short*)((char*)lds + t * 256 + 16 * ((d >> 3) ^ tc) + (d & 7) * 2);
    }
    *(short8*)(dstb + (size_t)d * 2048 + t0 + 8 * tc) = u;
  }
}

// ---------------- GEMM: C[M][N] = A[M][K] * Bt[N][K]^T + bias, m97 structure ----------------
template<bool BF16OUT>
__global__ __launch_bounds__(256, 2) void gemm_bt(
    const unsigned short* __restrict__ A, const unsigned short* __restrict__ Bt,
    const float* __restrict__ bias, void* __restrict__ Cout, int M, int N, int K) {
  __shared__ __align__(16) unsigned short Asl[128 * 64];
  __shared__ __align__(16) unsigned short Bsl[128 * 64];
  int tid = threadIdx.x;
  int lane = tid & 63, w = tid >> 6;
  int wr = w >> 1, wc = w & 1;
  int m0 = blockIdx.y * 128, n0 = blockIdx.x * 128;

  f32x4 acc[4][4];
  #pragma unroll
  for (int i = 0; i < 4; i++)
    #pragma unroll
    for (int j = 0; j < 4; j++)
      #pragma unroll
      for (int r = 0; r < 4; r++) acc[i][j][r] = 0.f;

  int srow = w * 32 + (lane >> 3);
  int kc8 = (lane & 7) * 8;
  const unsigned short* Aptr = A + (size_t)(m0 + srow) * K + kc8;
  const unsigned short* Bptr = Bt + (size_t)(n0 + srow) * K + kc8;
  unsigned short* AslW = Asl + w * 4 * 512;
  unsigned short* BslW = Bsl + w * 4 * 512;

  for (int k0 = 0; k0 < K; k0 += 64) {
    __syncthreads();
    #pragma unroll
    for (int i = 0; i < 4; i++) {
      __builtin_amdgcn_global_load_lds(
        (const __attribute__((address_space(1))) unsigned int*)(Aptr + (size_t)i * 8 * K + k0),
        (__attribute__((address_space(3))) unsigned int*)(AslW + i * 512), 16, 0, 0);
      __builtin_amdgcn_global_load_lds(
        (const __attribute__((address_space(1))) unsigned int*)(Bptr + (size_t)i * 8 * K + k0),
        (__attribute__((address_space(3))) unsigned int*)(BslW + i * 512), 16, 0, 0);
    }
    __syncthreads();
    #pragma unroll
    for (int ks = 0; ks < 2; ks++) {
      short8 af[4], bfr[4];
      #pragma unroll
      for (int mi = 0; mi < 4; mi++)
        af[mi] = *(const short8*)(Asl + (wr * 64 + mi * 16 + (lane & 15)) * 64 + ks * 32 + (lane >> 4) * 8);
      #pragma unroll
      for (int ni = 0; ni < 4; ni++)
        bfr[ni] = *(const short8*)(Bsl + (wc * 64 + ni * 16 + (lane & 15)) * 64 + ks * 32 + (lane >> 4) * 8);
      #pragma unroll
      for (int mi = 0; mi < 4; mi++)
        #pragma unroll
        for (int ni = 0; ni < 4; ni++)
          acc[mi][ni] = __builtin_amdgcn_mfma_f32_16x16x32_bf16(af[mi], bfr[ni], acc[mi][ni], 0, 0, 0);
    }
  }
  int cl = lane & 15, rq = lane >> 4;
  #pragma unroll
  for (int mi = 0; mi < 4; mi++) {
    #pragma unroll
    for (int ni = 0; ni < 4; ni++) {
      int gn = n0 + wc * 64 + ni * 16 + cl;
      float bv = bias[gn];
      #pragma unroll
      for (int r = 0; r < 4; r++) {
        int gm = m0 + wr * 64 + mi * 16 + rq * 4 + r;
        float v = acc[mi][ni][r] + bv;
        if (BF16OUT) ((unsigned short*)Cout)[(size_t)gm * N + gn] = f2bf(v);
        else ((float*)Cout)[(size_t)gm * N + gn] = v;
      }
    }
  }
}

// ---------------- flash attention v3: barrier-free, LDS-free, direct-L2 fragments ----------
// Qr [B][16][T][128] bf16 (pre-scaled by (1/sqrt(128))*log2(e)); Kr [B][4][T][128]; Vt [B][4][128][T]
// 1 wave per block, 32 q rows per wave. grid = 2048 blocks.
// bid -> XCD chunk swizzle: each XCD works one (b,kh) K/V set (L2-resident ~1MB); heavy q-tiles first.
__global__ __launch_bounds__(64) void attn_kernel(
    const unsigned short* __restrict__ Qr, const unsigned short* __restrict__ Kr,
    const unsigned short* __restrict__ Vt, unsigned short* __restrict__ O) {
  const int lane = threadIdx.x;
  const int l31 = lane & 31;
  const int hf = lane >> 5;
  const int bid = blockIdx.x;
  const int swz = (bid & 7) * 256 + (bid >> 3);   // XCD gets contiguous 256-chunk
  const int bh = swz >> 6;                        // 4 consecutive heads share (b,kh)
  const int qtile = 63 - (swz & 63);              // heavy (long) q-tiles launch first
  const int b = bh >> 4, h = bh & 15;
  const int kh = h >> 2;
  const int qw = qtile * 32;                      // lane's q = qw + l31

  // Q as B-operand fragments: col=lane&31 = q, k = s*16 + 8*hf + e
  const unsigned short* qbase = Qr + (((size_t)(b * 16 + h)) * 2048 + (qw + l31)) * 128;
  short8 qf[8];
  #pragma unroll
  for (int s = 0; s < 8; s++)
    qf[s] = *(const short8*)(qbase + s * 16 + hf * 8);

  float m_r = -3.0e38f, l_r = 0.f;
  f32x16 oacc[4];
  #pragma unroll
  for (int dt = 0; dt < 4; dt++)
    #pragma unroll
    for (int r = 0; r < 16; r++) oacc[dt][r] = 0.f;

  const unsigned short* kbase = Kr + ((size_t)(b * 4 + kh)) * 2048 * 128;
  const unsigned short* vbase = Vt + ((size_t)(b * 4 + kh)) * 128 * 2048;

  const int ntiles = (qtile >> 1) + 1;
  for (int kt = 0; kt < ntiles; kt++) {
    const int kv0 = kt * 64;

    // S^T[kv][q] = K · Q^T : two 32x32 tiles; A-frag K rows straight from L2
    f32x16 sc[2];
    #pragma unroll
    for (int ct = 0; ct < 2; ct++) {
      #pragma unroll
      for (int r = 0; r < 16; r++) sc[ct][r] = 0.f;
      #pragma unroll
      for (int s = 0; s < 8; s++) {
        short8 kf = *(const short8*)(kbase + (size_t)(kv0 + ct * 32 + l31) * 128 + s * 16 + hf * 8);
        sc[ct] = __builtin_amdgcn_mfma_f32_32x32x16_bf16(kf, qf[s], sc[ct], 0, 0, 0);
      }
    }

    // prefetch V fragments now so L2 latency hides under softmax VALU
    short8 vf[4][4];
    #pragma unroll
    for (int dt = 0; dt < 4; dt++)
      #pragma unroll
      for (int ks = 0; ks < 4; ks++)
        vf[dt][ks] = *(const short8*)(vbase + (size_t)(dt * 32 + l31) * 2048 + kv0 + ks * 16 + hf * 8);

    // causal mask (diagonal tiles only): C row = kv, col = q
    if (kv0 + 63 > qw) {
      #pragma unroll
      for (int ct = 0; ct < 2; ct++)
        #pragma unroll
        for (int r = 0; r < 16; r++) {
          int kg = kv0 + ct * 32 + (r & 3) + 8 * (r >> 2) + 4 * hf;
          if (kg > qw + l31) sc[ct][r] = -3.0e38f;
        }
    }
    // in-register row softmax (lane owns q = qw+l31; halves combined via shfl_xor 32)
    float mx[16];
    #pragma unroll
    for (int r = 0; r < 16; r++) mx[r] = fmaxf(sc[0][r], sc[1][r]);
    #pragma unroll
    for (int s2 = 8; s2 >= 1; s2 >>= 1)
      #pragma unroll
      for (int i = 0; i < 8; i++) if (i < s2) mx[i] = fmaxf(mx[i], mx[i + s2]);
    float tm = fmaxf(mx[0], __shfl_xor(mx[0], 32));
    float mn = fmaxf(m_r, tm);
    float al = __builtin_amdgcn_exp2f(m_r - mn);
    m_r = mn;
    #pragma unroll
    for (int ct = 0; ct < 2; ct++)
      #pragma unroll
      for (int r = 0; r < 16; r++) sc[ct][r] = __builtin_amdgcn_exp2f(sc[ct][r] - mn);
    float sm[16];
    #pragma unroll
    for (int r = 0; r < 16; r++) sm[r] = sc[0][r] + sc[1][r];
    #pragma unroll
    for (int s2 = 8; s2 >= 1; s2 >>= 1)
      #pragma unroll
      for (int i = 0; i < 8; i++) if (i < s2) sm[i] += sm[i + s2];
    float rs = sm[0] + __shfl_xor(sm[0], 32);
    l_r = l_r * al + rs;

    // repack P -> A-fragments: 16 cvt_pk + 8 permlane32_swap
    short8 pa[4];
    #pragma unroll
    for (int ks = 0; ks < 4; ks++) {
      const int ct = ks >> 1, kb = (ks & 1) * 8;
      unsigned int A0 = cvtpk_bf16(sc[ct][kb + 0], sc[ct][kb + 1]);
      unsigned int A1 = cvtpk_bf16(sc[ct][kb + 2], sc[ct][kb + 3]);
      unsigned int B0 = cvtpk_bf16(sc[ct][kb + 4], sc[ct][kb + 5]);
      unsigned int B1 = cvtpk_bf16(sc[ct][kb + 6], sc[ct][kb + 7]);
      plswap32(A0, B0);
      plswap32(A1, B1);
      union { unsigned int wds[4]; short8 s8; } u;
      u.wds[0] = A0; u.wds[1] = A1; u.wds[2] = B0; u.wds[3] = B1;
      pa[ks] = u.s8;
    }
    // rescale O rows by al (cross-lane broadcast, register-only)
    #pragma unroll
    for (int r = 0; r < 16; r++) {
      float alr = bcast32(al, (r & 3) + 8 * (r >> 2) + 4 * hf);
      #pragma unroll
      for (int dt = 0; dt < 4; dt++) oacc[dt][r] *= alr;
    }
    // PV: O[32q x 128d] += P[32x64] * V[64x128]
    #pragma unroll
    for (int dt = 0; dt < 4; dt++)
      #pragma unroll
      for (int ks = 0; ks < 4; ks++)
        oacc[dt] = __builtin_amdgcn_mfma_f32_32x32x16_bf16(pa[ks], vf[dt][ks], oacc[dt], 0, 0, 0);
  }
  // epilogue: broadcast 1/l per row, write O[b][q][h*128 + d]
  float invl = 1.0f / l_r;
  #pragma unroll
  for (int r = 0; r < 16; r++) {
    int rloc = (r & 3) + 8 * (r >> 2) + 4 * hf;
    float inv = bcast32(invl, rloc);
    int qg = qw + rloc;
    unsigned short* orow = O + ((size_t)(b * 2048 + qg)) * 2048 + h * 128;
    #pragma unroll
    for (int dt = 0; dt < 4; dt++)
      orow[dt * 32 + l31] = f2bf(oacc[dt][r] * inv);
  }
}

// ---------------- launch ----------------
extern "C" void kernel_launch(void* const* d_in, const int* in_sizes, int n_in,
                              void* d_out, int out_size, void* d_ws, size_t ws_size,
                              hipStream_t stream) {
  (void)in_sizes; (void)n_in; (void)out_size; (void)ws_size;
  const float* x  = (const float*)d_in[0];
  const float* Wq = (const float*)d_in[1];
  const float* bq = (const float*)d_in[2];
  const float* Wk = (const float*)d_in[3];
  const float* bk = (const float*)d_in[4];
  const float* Wv = (const float*)d_in[5];
  const float* bv = (const float*)d_in[6];
  const float* Wo = (const float*)d_in[7];
  const float* bo = (const float*)d_in[8];
  const int*   sp = (const int*)d_in[9];

  char* ws = (char*)d_ws;
  unsigned short* xb    = (unsigned short*)ws;                // 16,777,216 B (reused as Obuf)
  unsigned short* Wqkvt = (unsigned short*)(ws + 16777216);   // 12,582,912
  unsigned short* Wot   = (unsigned short*)(ws + 29360128);   //  8,388,608
  unsigned short* QKVb  = (unsigned short*)(ws + 37748736);   // 25,165,824 (bf16 [4096][3072])
  float* cost           = (float*)(ws + 62914560);            //    262,144
  float* sint           = (float*)(ws + 63176704);            //    262,144
  float* bcat           = (float*)(ws + 63438848);            //     12,288

  unsigned short* Obuf = xb;  // xb dead after GEMM1
  unsigned short* Qr = (unsigned short*)d_out;
  unsigned short* Kr = (unsigned short*)((char*)d_out + 16777216);
  unsigned short* Vtb = (unsigned short*)((char*)d_out + 20971520);

  mk_tables<<<256, 256, 0, stream>>>(cost, sint);
  bias_cat_k<<<12, 256, 0, stream>>>(bq, bk, bv, bcat);
  convx<<<4096, 256, 0, stream>>>(x, xb);
  transw<<<dim3(64, 64), 256, 0, stream>>>(Wq, Wqkvt, 2048);
  transw<<<dim3(16, 64), 256, 0, stream>>>(Wk, Wqkvt + (size_t)2048 * 2048, 512);
  transw<<<dim3(16, 64), 256, 0, stream>>>(Wv, Wqkvt + (size_t)2560 * 2048, 512);
  transw<<<dim3(64, 64), 256, 0, stream>>>(Wo, Wot, 2048);
  gemm_bt<true><<<dim3(24, 32), 256, 0, stream>>>(xb, Wqkvt, bcat, QKVb, 4096, 3072, 2048);
  // Q scale = (1/sqrt(128)) * log2(e) so softmax can use exp2 directly
  rope_scatter<16><<<16384, 256, 0, stream>>>(QKVb, cost, sint, sp, Qr, 0, 0.12751743f);
  rope_scatter<4><<<4096, 256, 0, stream>>>(QKVb, cost, sint, sp, Kr, 2048, 1.0f);
  vtrans<<<dim3(32, 8), 256, 0, stream>>>(QKVb, Vtb);
  attn_kernel<<<dim3(2048), 64, 0, stream>>>(Qr, Kr, Vtb, Obuf);
  gemm_bt<false><<<dim3(16, 32), 256, 0, stream>>>(Obuf, Wot, bo, (float*)d_out, 4096, 2048, 2048);
}

// Round 4
// 256.227 us; speedup vs baseline: 1.2220x; 1.2220x over previous
//
#include <hip/hip_runtime.h>

typedef __attribute__((ext_vector_type(8))) short short8;
typedef __attribute__((ext_vector_type(4))) float f32x4;
typedef __attribute__((ext_vector_type(16))) float f32x16;

#define DEVFN __device__ __forceinline__

DEVFN unsigned short f2bf(float f) {
  unsigned int u = __builtin_bit_cast(unsigned int, f);
  u += 0x7FFFu + ((u >> 16) & 1u);   // RNE
  return (unsigned short)(u >> 16);
}
DEVFN float bf2f(unsigned int u) { return __builtin_bit_cast(float, u << 16); }

DEVFN unsigned int cvtpk_bf16(float lo, float hi) {
  unsigned int d;
  asm("v_cvt_pk_bf16_f32 %0, %1, %2" : "=v"(d) : "v"(lo), "v"(hi));
  return d;
}
DEVFN void plswap32(unsigned int& a, unsigned int& b) {
  asm("v_permlane32_swap_b32 %0, %1" : "+v"(a), "+v"(b));
}
DEVFN float bcast32(float v, int srclane) {
  int r = __builtin_amdgcn_ds_bpermute(srclane * 4, __builtin_bit_cast(int, v));
  return __builtin_bit_cast(float, r);
}

// ---------------- prep kernels ----------------

// cos/sin tables: [2048 pos][32 freq]
__global__ __launch_bounds__(256) void mk_tables(float* __restrict__ cost, float* __restrict__ sint) {
  int gid = blockIdx.x * 256 + threadIdx.x;   // 65536
  int pos = gid >> 5, i = gid & 31;
  float theta = powf(10000.0f, -(float)(2 * i) / 64.0f);
  float ang = (float)pos * theta;
  cost[gid] = cosf(ang);
  sint[gid] = sinf(ang);
}

__global__ __launch_bounds__(256) void bias_cat_k(const float* __restrict__ bq, const float* __restrict__ bk,
                                                  const float* __restrict__ bv, float* __restrict__ out) {
  int i = blockIdx.x * 256 + threadIdx.x;  // 3072
  float v;
  if (i < 2048) v = bq[i];
  else if (i < 2560) v = bk[i - 2048];
  else v = bv[i - 2560];
  out[i] = v;
}

__global__ __launch_bounds__(256) void convx(const float* __restrict__ x, unsigned short* __restrict__ xb) {
  int gid = blockIdx.x * 256 + threadIdx.x;   // 1048576 threads, 8 f32 each
  const float4* xv = (const float4*)x;
  float4 a = xv[(size_t)gid * 2], b = xv[(size_t)gid * 2 + 1];
  short8 u;
  u[0] = (short)f2bf(a.x); u[1] = (short)f2bf(a.y); u[2] = (short)f2bf(a.z); u[3] = (short)f2bf(a.w);
  u[4] = (short)f2bf(b.x); u[5] = (short)f2bf(b.y); u[6] = (short)f2bf(b.z); u[7] = (short)f2bf(b.w);
  *(short8*)(xb + (size_t)gid * 8) = u;
}

// W [2048][ncols] f32 -> Wt [ncols][2048] bf16 (Wt pre-offset by caller)
__global__ __launch_bounds__(256) void transw(const float* __restrict__ W, unsigned short* __restrict__ Wt, int ncols) {
  __shared__ float lds[32][33];
  int n0 = blockIdx.x * 32, k0 = blockIdx.y * 32;
  int tx = threadIdx.x & 31, ty = threadIdx.x >> 5;
  #pragma unroll
  for (int i = 0; i < 4; i++) {
    int kr = ty + i * 8;
    lds[kr][tx] = W[(size_t)(k0 + kr) * ncols + n0 + tx];
  }
  __syncthreads();
  #pragma unroll
  for (int i = 0; i < 4; i++) {
    int nr = ty + i * 8;
    Wt[(size_t)(n0 + nr) * 2048 + k0 + tx] = f2bf(lds[tx][nr]);
  }
}

// ---------------- RoPE + scatter ----------------
template<int NH>
__global__ __launch_bounds__(256) void rope_scatter(const unsigned short* __restrict__ QKV,
    const float* __restrict__ cost, const float* __restrict__ sint, const int* __restrict__ spp,
    unsigned short* __restrict__ dst, int colOff, float scale) {
  constexpr int LOG2NH = (NH == 16) ? 4 : 2;
  int gid = blockIdx.x * 256 + threadIdx.x;
  int j = gid & 63;
  int h = (gid >> 6) & (NH - 1);
  int m = gid >> (6 + LOG2NH);
  int t = m & 2047;
  const unsigned short* src = QKV + (size_t)m * 3072 + colOff + h * 128 + 2 * j;
  unsigned int pair = *(const unsigned int*)src;
  float xv = bf2f(pair & 0xFFFFu), yv = bf2f(pair >> 16);
  float rx, ry;
  if (j < 32) {
    int pos = (spp[0] + t) & 2047;
    float c = cost[pos * 32 + j], s = sint[pos * 32 + j];
    rx = xv * c - yv * s;
    ry = xv * s + yv * c;
  } else { rx = xv; ry = yv; }
  rx *= scale; ry *= scale;
  size_t drow = ((size_t)((m >> 11) * NH + h)) * 2048 + t;
  unsigned int outp = (unsigned int)f2bf(rx) | ((unsigned int)f2bf(ry) << 16);
  *(unsigned int*)(dst + drow * 128 + 2 * j) = outp;
}

// ---------------- V transpose: QKV[.,2560+kh*128+d] -> Vt[b][kh][d][t] ----------------
__global__ __launch_bounds__(256) void vtrans(const unsigned short* __restrict__ QKV, unsigned short* __restrict__ Vt) {
  __shared__ __align__(16) unsigned short lds[64 * 128];  // swizzled [t][d]
  int tid = threadIdx.x;
  int t0 = blockIdx.x * 64;
  int bk = blockIdx.y;         // b*4 + kh
  const unsigned short* src = QKV + (size_t)(bk >> 2) * 2048 * 3072 + 2560 + (bk & 3) * 128;
  #pragma unroll
  for (int c = 0; c < 4; c++) {
    int idx = c * 256 + tid;
    int tr = idx >> 4, dc = idx & 15;
    short8 v = *(const short8*)(src + (size_t)(t0 + tr) * 3072 + dc * 8);
    *(short8*)((char*)lds + tr * 256 + 16 * (dc ^ (tr >> 3))) = v;
  }
  __syncthreads();
  unsigned short* dstb = Vt + (size_t)bk * 128 * 2048;
  #pragma unroll
  for (int c2 = 0; c2 < 4; c2++) {
    int idx2 = c2 * 256 + tid;
    int tc = idx2 & 7, d = idx2 >> 3;
    short8 u;
    #pragma unroll
    for (int e = 0; e < 8; e++) {
      int t = 8 * tc + e;
      u[e] = *(const short*)((char*)lds + t * 256 + 16 * ((d >> 3) ^ tc) + (d & 7) * 2);
    }
    *(short8*)(dstb + (size_t)d * 2048 + t0 + 8 * tc) = u;
  }
}

// ---------------- GEMM: C[M][N] = A[M][K] * Bt[N][K]^T + bias, m97 structure ----------------
template<bool BF16OUT>
__global__ __launch_bounds__(256, 2) void gemm_bt(
    const unsigned short* __restrict__ A, const unsigned short* __restrict__ Bt,
    const float* __restrict__ bias, void* __restrict__ Cout, int M, int N, int K) {
  __shared__ __align__(16) unsigned short Asl[128 * 64];
  __shared__ __align__(16) unsigned short Bsl[128 * 64];
  int tid = threadIdx.x;
  int lane = tid & 63, w = tid >> 6;
  int wr = w >> 1, wc = w & 1;
  int m0 = blockIdx.y * 128, n0 = blockIdx.x * 128;

  f32x4 acc[4][4];
  #pragma unroll
  for (int i = 0; i < 4; i++)
    #pragma unroll
    for (int j = 0; j < 4; j++)
      #pragma unroll
      for (int r = 0; r < 4; r++) acc[i][j][r] = 0.f;

  int srow = w * 32 + (lane >> 3);
  int kc8 = (lane & 7) * 8;
  const unsigned short* Aptr = A + (size_t)(m0 + srow) * K + kc8;
  const unsigned short* Bptr = Bt + (size_t)(n0 + srow) * K + kc8;
  unsigned short* AslW = Asl + w * 4 * 512;
  unsigned short* BslW = Bsl + w * 4 * 512;

  for (int k0 = 0; k0 < K; k0 += 64) {
    __syncthreads();
    #pragma unroll
    for (int i = 0; i < 4; i++) {
      __builtin_amdgcn_global_load_lds(
        (const __attribute__((address_space(1))) unsigned int*)(Aptr + (size_t)i * 8 * K + k0),
        (__attribute__((address_space(3))) unsigned int*)(AslW + i * 512), 16, 0, 0);
      __builtin_amdgcn_global_load_lds(
        (const __attribute__((address_space(1))) unsigned int*)(Bptr + (size_t)i * 8 * K + k0),
        (__attribute__((address_space(3))) unsigned int*)(BslW + i * 512), 16, 0, 0);
    }
    __syncthreads();
    #pragma unroll
    for (int ks = 0; ks < 2; ks++) {
      short8 af[4], bfr[4];
      #pragma unroll
      for (int mi = 0; mi < 4; mi++)
        af[mi] = *(const short8*)(Asl + (wr * 64 + mi * 16 + (lane & 15)) * 64 + ks * 32 + (lane >> 4) * 8);
      #pragma unroll
      for (int ni = 0; ni < 4; ni++)
        bfr[ni] = *(const short8*)(Bsl + (wc * 64 + ni * 16 + (lane & 15)) * 64 + ks * 32 + (lane >> 4) * 8);
      #pragma unroll
      for (int mi = 0; mi < 4; mi++)
        #pragma unroll
        for (int ni = 0; ni < 4; ni++)
          acc[mi][ni] = __builtin_amdgcn_mfma_f32_16x16x32_bf16(af[mi], bfr[ni], acc[mi][ni], 0, 0, 0);
    }
  }
  int cl = lane & 15, rq = lane >> 4;
  #pragma unroll
  for (int mi = 0; mi < 4; mi++) {
    #pragma unroll
    for (int ni = 0; ni < 4; ni++) {
      int gn = n0 + wc * 64 + ni * 16 + cl;
      float bv = bias[gn];
      #pragma unroll
      for (int r = 0; r < 4; r++) {
        int gm = m0 + wr * 64 + mi * 16 + rq * 4 + r;
        float v = acc[mi][ni][r] + bv;
        if (BF16OUT) ((unsigned short*)Cout)[(size_t)gm * N + gn] = f2bf(v);
        else ((float*)Cout)[(size_t)gm * N + gn] = v;
      }
    }
  }
}

// ---------------- flash attention v4: balanced 4-wave blocks + reg-prefetch staging ----------
// Qr [B][16][T][128] bf16 (pre-scaled by (1/sqrt(128))*log2(e)); Kr [B][4][T][128]; Vt [B][4][128][T]
// grid: 512 blocks x 256 thr. Block d: bx=d>>5 (0..15), bh=d&31. Wave w handles qtile:
//   {2bx, 2bx+1, 62-2bx, 63-2bx}[w] -> every block = exactly 66 wave-tile-units (perfect balance).
// Heavy blocks (bx=0) dispatch first (LPT). KV tile = 64, staged cooperatively by all 4 waves.
__global__ __launch_bounds__(256) void attn_kernel(
    const unsigned short* __restrict__ Qr, const unsigned short* __restrict__ Kr,
    const unsigned short* __restrict__ Vt, unsigned short* __restrict__ O) {
  __shared__ __align__(16) unsigned short K_lds[64 * 136];   // [kv][128 + 8 pad]
  __shared__ __align__(16) unsigned short V_lds[128 * 72];   // [d][64 + 8 pad]

  const int tid = threadIdx.x;
  const int lane = tid & 63;
  const int w = tid >> 6;
  const int l31 = lane & 31;
  const int hf = lane >> 5;
  const int dctl = blockIdx.x;
  const int bx = dctl >> 5;
  const int bh = dctl & 31;
  const int b = bh >> 4, h = bh & 15;
  const int kh = h >> 2;
  const int qt = (w < 2) ? (2 * bx + w) : (60 - 2 * bx + w);  // w=2 -> 62-2bx, w=3 -> 63-2bx
  const int qw = qt * 32;
  const int nw = (qt >> 1) + 1;        // kv64-tiles this wave needs
  const int nbt = 32 - bx;             // kv64-tiles this block stages

  // Q as B-operand fragments: col=lane&31 = q, k = s*16 + 8*hf + e
  const unsigned short* qbase = Qr + (((size_t)(b * 16 + h)) * 2048 + (qw + l31)) * 128;
  short8 qf[8];
  #pragma unroll
  for (int s = 0; s < 8; s++)
    qf[s] = *(const short8*)(qbase + s * 16 + hf * 8);

  float m_r = -3.0e38f, l_r = 0.f;
  f32x16 oacc[4];
  #pragma unroll
  for (int dt = 0; dt < 4; dt++)
    #pragma unroll
    for (int r = 0; r < 16; r++) oacc[dt][r] = 0.f;

  const unsigned short* kbase = Kr + ((size_t)(b * 4 + kh)) * 2048 * 128;
  const unsigned short* vbase = Vt + ((size_t)(b * 4 + kh)) * 128 * 2048;

  // staging geometry: K 64x128 in 16B chunks (1024 = 4/thread); V^T 128x64 (1024 = 4/thread)
  int krow[4], kcol[4], vdr[4], vkc[4];
  #pragma unroll
  for (int c = 0; c < 4; c++) {
    int idx = c * 256 + tid;
    krow[c] = idx >> 4; kcol[c] = idx & 15;
    vdr[c] = idx >> 3;  vkc[c] = idx & 7;
  }
  short8 kreg[4], vreg[4];
  #pragma unroll
  for (int c = 0; c < 4; c++) {        // prologue: issue tile 0
    kreg[c] = *(const short8*)(kbase + (size_t)krow[c] * 128 + kcol[c] * 8);
    vreg[c] = *(const short8*)(vbase + (size_t)vdr[c] * 2048 + vkc[c] * 8);
  }

  for (int kt = 0; kt < nbt; kt++) {
    const int kv0 = kt * 64;
    __syncthreads();                   // prev compute done reading LDS; prefetch regs ready
    #pragma unroll
    for (int c = 0; c < 4; c++) {
      *(short8*)((char*)K_lds + krow[c] * 272 + kcol[c] * 16) = kreg[c];
      *(short8*)((char*)V_lds + vdr[c] * 144 + vkc[c] * 16) = vreg[c];
    }
    __syncthreads();                   // writes visible
    if (kt + 1 < nbt) {                // issue next tile's loads; fly during compute
      const int kn = kv0 + 64;
      #pragma unroll
      for (int c = 0; c < 4; c++) {
        kreg[c] = *(const short8*)(kbase + (size_t)(kn + krow[c]) * 128 + kcol[c] * 8);
        vreg[c] = *(const short8*)(vbase + (size_t)vdr[c] * 2048 + kn + vkc[c] * 8);
      }
    }
    if (kt < nw) {
      // S^T[kv][q] = K · Q^T : two 32x32 tiles
      f32x16 sc[2];
      #pragma unroll
      for (int ct = 0; ct < 2; ct++) {
        #pragma unroll
        for (int r = 0; r < 16; r++) sc[ct][r] = 0.f;
        #pragma unroll
        for (int s = 0; s < 8; s++) {
          short8 kf = *(const short8*)((char*)K_lds + (ct * 32 + l31) * 272 + s * 32 + hf * 16);
          sc[ct] = __builtin_amdgcn_mfma_f32_32x32x16_bf16(kf, qf[s], sc[ct], 0, 0, 0);
        }
      }
      // causal mask (diagonal tile only): C row = kv, col = q
      if (kv0 + 63 > qw) {
        #pragma unroll
        for (int ct = 0; ct < 2; ct++)
          #pragma unroll
          for (int r = 0; r < 16; r++) {
            int kg = kv0 + ct * 32 + (r & 3) + 8 * (r >> 2) + 4 * hf;
            if (kg > qw + l31) sc[ct][r] = -3.0e38f;
          }
      }
      // row max (lane pair l31 / l31+32 share q-row)
      float mx[16];
      #pragma unroll
      for (int r = 0; r < 16; r++) mx[r] = fmaxf(sc[0][r], sc[1][r]);
      #pragma unroll
      for (int s2 = 8; s2 >= 1; s2 >>= 1)
        #pragma unroll
        for (int i = 0; i < 8; i++) if (i < s2) mx[i] = fmaxf(mx[i], mx[i + s2]);
      float tm = fmaxf(mx[0], __shfl_xor(mx[0], 32));
      // defer-max: only rescale when max grows past threshold (exp2 domain, P <= 2^8)
      if (__any(tm > m_r + 8.0f)) {
        float mn = fmaxf(m_r, tm);
        float al = __builtin_amdgcn_exp2f(m_r - mn);
        m_r = mn;
        l_r *= al;
        #pragma unroll
        for (int r = 0; r < 16; r++) {
          float alr = bcast32(al, (r & 3) + 8 * (r >> 2) + 4 * hf);
          #pragma unroll
          for (int dt = 0; dt < 4; dt++) oacc[dt][r] *= alr;
        }
      }
      #pragma unroll
      for (int ct = 0; ct < 2; ct++)
        #pragma unroll
        for (int r = 0; r < 16; r++) sc[ct][r] = __builtin_amdgcn_exp2f(sc[ct][r] - m_r);
      float sm[16];
      #pragma unroll
      for (int r = 0; r < 16; r++) sm[r] = sc[0][r] + sc[1][r];
      #pragma unroll
      for (int s2 = 8; s2 >= 1; s2 >>= 1)
        #pragma unroll
        for (int i = 0; i < 8; i++) if (i < s2) sm[i] += sm[i + s2];
      l_r += sm[0];                    // partial (own 32 kv); combined in epilogue

      // repack P -> A-fragments: 16 cvt_pk + 8 permlane32_swap
      short8 pa[4];
      #pragma unroll
      for (int ks = 0; ks < 4; ks++) {
        const int ct = ks >> 1, kb = (ks & 1) * 8;
        unsigned int A0 = cvtpk_bf16(sc[ct][kb + 0], sc[ct][kb + 1]);
        unsigned int A1 = cvtpk_bf16(sc[ct][kb + 2], sc[ct][kb + 3]);
        unsigned int B0 = cvtpk_bf16(sc[ct][kb + 4], sc[ct][kb + 5]);
        unsigned int B1 = cvtpk_bf16(sc[ct][kb + 6], sc[ct][kb + 7]);
        plswap32(A0, B0);
        plswap32(A1, B1);
        union { unsigned int wds[4]; short8 s8; } u;
        u.wds[0] = A0; u.wds[1] = A1; u.wds[2] = B0; u.wds[3] = B1;
        pa[ks] = u.s8;
      }
      // PV: O[32q x 128d] += P[32x64] * V[64x128]
      #pragma unroll
      for (int dt = 0; dt < 4; dt++)
        #pragma unroll
        for (int ks = 0; ks < 4; ks++) {
          short8 vf = *(const short8*)((char*)V_lds + (dt * 32 + l31) * 144 + ks * 32 + hf * 16);
          oacc[dt] = __builtin_amdgcn_mfma_f32_32x32x16_bf16(pa[ks], vf, oacc[dt], 0, 0, 0);
        }
    }
  }
  // epilogue: combine l halves, broadcast 1/l per row, write O[b][q][h*128 + d]
  float invl = 1.0f / (l_r + __shfl_xor(l_r, 32));
  #pragma unroll
  for (int r = 0; r < 16; r++) {
    int rloc = (r & 3) + 8 * (r >> 2) + 4 * hf;
    float inv = bcast32(invl, rloc);
    int qg = qw + rloc;
    unsigned short* orow = O + ((size_t)(b * 2048 + qg)) * 2048 + h * 128;
    #pragma unroll
    for (int dt = 0; dt < 4; dt++)
      orow[dt * 32 + l31] = f2bf(oacc[dt][r] * inv);
  }
}

// ---------------- launch ----------------
extern "C" void kernel_launch(void* const* d_in, const int* in_sizes, int n_in,
                              void* d_out, int out_size, void* d_ws, size_t ws_size,
                              hipStream_t stream) {
  (void)in_sizes; (void)n_in; (void)out_size; (void)ws_size;
  const float* x  = (const float*)d_in[0];
  const float* Wq = (const float*)d_in[1];
  const float* bq = (const float*)d_in[2];
  const float* Wk = (const float*)d_in[3];
  const float* bk = (const float*)d_in[4];
  const float* Wv = (const float*)d_in[5];
  const float* bv = (const float*)d_in[6];
  const float* Wo = (const float*)d_in[7];
  const float* bo = (const float*)d_in[8];
  const int*   sp = (const int*)d_in[9];

  char* ws = (char*)d_ws;
  unsigned short* xb    = (unsigned short*)ws;                // 16,777,216 B (reused as Obuf)
  unsigned short* Wqkvt = (unsigned short*)(ws + 16777216);   // 12,582,912
  unsigned short* Wot   = (unsigned short*)(ws + 29360128);   //  8,388,608
  unsigned short* QKVb  = (unsigned short*)(ws + 37748736);   // 25,165,824 (bf16 [4096][3072])
  float* cost           = (float*)(ws + 62914560);            //    262,144
  float* sint           = (float*)(ws + 63176704);            //    262,144
  float* bcat           = (float*)(ws + 63438848);            //     12,288

  unsigned short* Obuf = xb;  // xb dead after GEMM1
  unsigned short* Qr = (unsigned short*)d_out;
  unsigned short* Kr = (unsigned short*)((char*)d_out + 16777216);
  unsigned short* Vtb = (unsigned short*)((char*)d_out + 20971520);

  mk_tables<<<256, 256, 0, stream>>>(cost, sint);
  bias_cat_k<<<12, 256, 0, stream>>>(bq, bk, bv, bcat);
  convx<<<4096, 256, 0, stream>>>(x, xb);
  transw<<<dim3(64, 64), 256, 0, stream>>>(Wq, Wqkvt, 2048);
  transw<<<dim3(16, 64), 256, 0, stream>>>(Wk, Wqkvt + (size_t)2048 * 2048, 512);
  transw<<<dim3(16, 64), 256, 0, stream>>>(Wv, Wqkvt + (size_t)2560 * 2048, 512);
  transw<<<dim3(64, 64), 256, 0, stream>>>(Wo, Wot, 2048);
  gemm_bt<true><<<dim3(24, 32), 256, 0, stream>>>(xb, Wqkvt, bcat, QKVb, 4096, 3072, 2048);
  // Q scale = (1/sqrt(128)) * log2(e) so softmax can use exp2 directly
  rope_scatter<16><<<16384, 256, 0, stream>>>(QKVb, cost, sint, sp, Qr, 0, 0.12751743f);
  rope_scatter<4><<<4096, 256, 0, stream>>>(QKVb, cost, sint, sp, Kr, 2048, 1.0f);
  vtrans<<<dim3(32, 8), 256, 0, stream>>>(QKVb, Vtb);
  attn_kernel<<<dim3(512), 256, 0, stream>>>(Qr, Kr, Vtb, Obuf);
  gemm_bt<false><<<dim3(16, 32), 256, 0, stream>>>(Obuf, Wot, bo, (float*)d_out, 4096, 2048, 2048);
}

// Round 5
// 237.860 us; speedup vs baseline: 1.3164x; 1.0772x over previous
//
#include <hip/hip_runtime.h>

typedef __attribute__((ext_vector_type(8))) short short8;
typedef __attribute__((ext_vector_type(4))) float f32x4;
typedef __attribute__((ext_vector_type(16))) float f32x16;

#define DEVFN __device__ __forceinline__

DEVFN unsigned short f2bf(float f) {
  unsigned int u = __builtin_bit_cast(unsigned int, f);
  u += 0x7FFFu + ((u >> 16) & 1u);   // RNE
  return (unsigned short)(u >> 16);
}
DEVFN float bf2f(unsigned int u) { return __builtin_bit_cast(float, u << 16); }

DEVFN unsigned int cvtpk_bf16(float lo, float hi) {
  unsigned int d;
  asm("v_cvt_pk_bf16_f32 %0, %1, %2" : "=v"(d) : "v"(lo), "v"(hi));
  return d;
}
DEVFN void plswap32(unsigned int& a, unsigned int& b) {
  asm("v_permlane32_swap_b32 %0, %1" : "+v"(a), "+v"(b));
}
DEVFN float bcast32(float v, int srclane) {
  int r = __builtin_amdgcn_ds_bpermute(srclane * 4, __builtin_bit_cast(int, v));
  return __builtin_bit_cast(float, r);
}

// ---------------- prep kernels ----------------

// cos/sin tables: [2048 pos][32 freq]
__global__ __launch_bounds__(256) void mk_tables(float* __restrict__ cost, float* __restrict__ sint) {
  int gid = blockIdx.x * 256 + threadIdx.x;   // 65536
  int pos = gid >> 5, i = gid & 31;
  float theta = powf(10000.0f, -(float)(2 * i) / 64.0f);
  float ang = (float)pos * theta;
  cost[gid] = cosf(ang);
  sint[gid] = sinf(ang);
}

__global__ __launch_bounds__(256) void bias_cat_k(const float* __restrict__ bq, const float* __restrict__ bk,
                                                  const float* __restrict__ bv, float* __restrict__ out) {
  int i = blockIdx.x * 256 + threadIdx.x;  // 3072
  float v;
  if (i < 2048) v = bq[i];
  else if (i < 2560) v = bk[i - 2048];
  else v = bv[i - 2560];
  out[i] = v;
}

__global__ __launch_bounds__(256) void convx(const float* __restrict__ x, unsigned short* __restrict__ xb) {
  int gid = blockIdx.x * 256 + threadIdx.x;   // 1048576 threads, 8 f32 each
  const float4* xv = (const float4*)x;
  float4 a = xv[(size_t)gid * 2], b = xv[(size_t)gid * 2 + 1];
  short8 u;
  u[0] = (short)f2bf(a.x); u[1] = (short)f2bf(a.y); u[2] = (short)f2bf(a.z); u[3] = (short)f2bf(a.w);
  u[4] = (short)f2bf(b.x); u[5] = (short)f2bf(b.y); u[6] = (short)f2bf(b.z); u[7] = (short)f2bf(b.w);
  *(short8*)(xb + (size_t)gid * 8) = u;
}

// W [2048][ncols] f32 -> Wt [ncols][2048] bf16 (Wt pre-offset by caller)
__global__ __launch_bounds__(256) void transw(const float* __restrict__ W, unsigned short* __restrict__ Wt, int ncols) {
  __shared__ float lds[32][33];
  int n0 = blockIdx.x * 32, k0 = blockIdx.y * 32;
  int tx = threadIdx.x & 31, ty = threadIdx.x >> 5;
  #pragma unroll
  for (int i = 0; i < 4; i++) {
    int kr = ty + i * 8;
    lds[kr][tx] = W[(size_t)(k0 + kr) * ncols + n0 + tx];
  }
  __syncthreads();
  #pragma unroll
  for (int i = 0; i < 4; i++) {
    int nr = ty + i * 8;
    Wt[(size_t)(n0 + nr) * 2048 + k0 + tx] = f2bf(lds[tx][nr]);
  }
}

// ---------------- RoPE + scatter into MFMA A-fragment order ----------------
// QKV bf16 [4096][3072] -> dst per head [tile32=t>>5][s=d>>4][lane=(d>>3&1)*32+(t&31)] x 8 elems
template<int NH>
__global__ __launch_bounds__(256) void rope_scatter(const unsigned short* __restrict__ QKV,
    const float* __restrict__ cost, const float* __restrict__ sint, const int* __restrict__ spp,
    unsigned short* __restrict__ dst, int colOff, float scale) {
  constexpr int LOG2NH = (NH == 16) ? 4 : 2;
  int gid = blockIdx.x * 256 + threadIdx.x;
  int j = gid & 63;
  int h = (gid >> 6) & (NH - 1);
  int m = gid >> (6 + LOG2NH);
  int t = m & 2047;
  int b = m >> 11;
  const unsigned short* src = QKV + (size_t)m * 3072 + colOff + h * 128 + 2 * j;
  unsigned int pair = *(const unsigned int*)src;
  float xv = bf2f(pair & 0xFFFFu), yv = bf2f(pair >> 16);
  float rx, ry;
  if (j < 32) {
    int pos = (spp[0] + t) & 2047;
    float c = cost[pos * 32 + j], s = sint[pos * 32 + j];
    rx = xv * c - yv * s;
    ry = xv * s + yv * c;
  } else { rx = xv; ry = yv; }
  rx *= scale; ry *= scale;
  int d0 = 2 * j;
  size_t off = (size_t)(b * NH + h) * 262144 + (t >> 5) * 4096 + (d0 >> 4) * 512
             + ((d0 >> 3) & 1) * 256 + (t & 31) * 8 + (d0 & 7);
  unsigned int outp = (unsigned int)f2bf(rx) | ((unsigned int)f2bf(ry) << 16);
  *(unsigned int*)(dst + off) = outp;
}

// ---------------- V transpose into PV B-fragment order ----------------
// QKV[.,2560+kh*128+d] -> VF per (b,kh): [vtile64][dt=d>>5][ks][lane=(hf)*32+(d&31)] x 8 kv-elems
__global__ __launch_bounds__(256) void vtrans(const unsigned short* __restrict__ QKV, unsigned short* __restrict__ VF) {
  __shared__ __align__(16) unsigned short lds[64 * 128];  // swizzled [t][d]
  int tid = threadIdx.x;
  int t0 = blockIdx.x * 64;
  int bk = blockIdx.y;         // b*4 + kh
  const unsigned short* src = QKV + (size_t)(bk >> 2) * 2048 * 3072 + 2560 + (bk & 3) * 128;
  #pragma unroll
  for (int c = 0; c < 4; c++) {
    int idx = c * 256 + tid;
    int tr = idx >> 4, dc = idx & 15;
    short8 v = *(const short8*)(src + (size_t)(t0 + tr) * 3072 + dc * 8);
    *(short8*)((char*)lds + tr * 256 + 16 * (dc ^ (tr >> 3))) = v;
  }
  __syncthreads();
  unsigned short* dstb = VF + (size_t)bk * 262144;
  #pragma unroll
  for (int c2 = 0; c2 < 4; c2++) {
    int idx2 = c2 * 256 + tid;
    int tc = idx2 & 7, d = idx2 >> 3;
    short8 u;
    #pragma unroll
    for (int e = 0; e < 8; e++) {
      int t = 8 * tc + e;
      u[e] = *(const short*)((char*)lds + t * 256 + 16 * ((d >> 3) ^ tc) + (d & 7) * 2);
    }
    size_t off = (size_t)(t0 >> 6) * 8192 + ((d >> 5) * 4 + ((tc >> 1) & 3)) * 512
               + (tc & 1) * 256 + (d & 31) * 8;
    *(short8*)(dstb + off) = u;
  }
}

// ---------------- GEMM: C[M][N] = A[M][K] * Bt[N][K]^T + bias, m97 structure ----------------
template<bool BF16OUT>
__global__ __launch_bounds__(256, 2) void gemm_bt(
    const unsigned short* __restrict__ A, const unsigned short* __restrict__ Bt,
    const float* __restrict__ bias, void* __restrict__ Cout, int M, int N, int K) {
  __shared__ __align__(16) unsigned short Asl[128 * 64];
  __shared__ __align__(16) unsigned short Bsl[128 * 64];
  int tid = threadIdx.x;
  int lane = tid & 63, w = tid >> 6;
  int wr = w >> 1, wc = w & 1;
  int m0 = blockIdx.y * 128, n0 = blockIdx.x * 128;

  f32x4 acc[4][4];
  #pragma unroll
  for (int i = 0; i < 4; i++)
    #pragma unroll
    for (int j = 0; j < 4; j++)
      #pragma unroll
      for (int r = 0; r < 4; r++) acc[i][j][r] = 0.f;

  int srow = w * 32 + (lane >> 3);
  int kc8 = (lane & 7) * 8;
  const unsigned short* Aptr = A + (size_t)(m0 + srow) * K + kc8;
  const unsigned short* Bptr = Bt + (size_t)(n0 + srow) * K + kc8;
  unsigned short* AslW = Asl + w * 4 * 512;
  unsigned short* BslW = Bsl + w * 4 * 512;

  for (int k0 = 0; k0 < K; k0 += 64) {
    __syncthreads();
    #pragma unroll
    for (int i = 0; i < 4; i++) {
      __builtin_amdgcn_global_load_lds(
        (const __attribute__((address_space(1))) unsigned int*)(Aptr + (size_t)i * 8 * K + k0),
        (__attribute__((address_space(3))) unsigned int*)(AslW + i * 512), 16, 0, 0);
      __builtin_amdgcn_global_load_lds(
        (const __attribute__((address_space(1))) unsigned int*)(Bptr + (size_t)i * 8 * K + k0),
        (__attribute__((address_space(3))) unsigned int*)(BslW + i * 512), 16, 0, 0);
    }
    __syncthreads();
    #pragma unroll
    for (int ks = 0; ks < 2; ks++) {
      short8 af[4], bfr[4];
      #pragma unroll
      for (int mi = 0; mi < 4; mi++)
        af[mi] = *(const short8*)(Asl + (wr * 64 + mi * 16 + (lane & 15)) * 64 + ks * 32 + (lane >> 4) * 8);
      #pragma unroll
      for (int ni = 0; ni < 4; ni++)
        bfr[ni] = *(const short8*)(Bsl + (wc * 64 + ni * 16 + (lane & 15)) * 64 + ks * 32 + (lane >> 4) * 8);
      #pragma unroll
      for (int mi = 0; mi < 4; mi++)
        #pragma unroll
        for (int ni = 0; ni < 4; ni++)
          acc[mi][ni] = __builtin_amdgcn_mfma_f32_16x16x32_bf16(af[mi], bfr[ni], acc[mi][ni], 0, 0, 0);
    }
  }
  int cl = lane & 15, rq = lane >> 4;
  #pragma unroll
  for (int mi = 0; mi < 4; mi++) {
    #pragma unroll
    for (int ni = 0; ni < 4; ni++) {
      int gn = n0 + wc * 64 + ni * 16 + cl;
      float bv = bias[gn];
      #pragma unroll
      for (int r = 0; r < 4; r++) {
        int gm = m0 + wr * 64 + mi * 16 + rq * 4 + r;
        float v = acc[mi][ni][r] + bv;
        if (BF16OUT) ((unsigned short*)Cout)[(size_t)gm * N + gn] = f2bf(v);
        else ((float*)Cout)[(size_t)gm * N + gn] = v;
      }
    }
  }
}

// ---------------- flash attention v5: barrier-free, fragment-order global loads ----------
// QF per (b,h): [qtile32][s][lane]x8 ; KF per (b,kh): same ; VF per (b,kh): [vtile64][dt*4+ks][lane]x8
// grid: 256 blocks x 512 thr = 2048 independent waves, whole grid resident (1 block/CU).
// bid&7 -> (b,kh) so each XCD's blocks share one 1MB K/V set. SIMD pairing (w, w+4) sums to 33 tiles.
__global__ __launch_bounds__(512, 2) void attn_kernel(
    const unsigned short* __restrict__ QF, const unsigned short* __restrict__ KF,
    const unsigned short* __restrict__ VF, unsigned short* __restrict__ O) {
  const int tid = threadIdx.x;
  const int lane = tid & 63;
  const int w = tid >> 6;
  const int l31 = lane & 31;
  const int hf = lane >> 5;
  const int g = blockIdx.x & 7, j = blockIdx.x >> 3;
  const int b = g >> 2, kh = g & 3;
  const int h = kh * 4 + (j & 3);
  const int i4 = (j >> 2) * 4;
  const int qt = (w < 4) ? (i4 + w) : (67 - i4 - w);
  const int qw = qt * 32;
  const int nw = (qt >> 1) + 1;

  const unsigned short* qh  = QF + (size_t)(b * 16 + h) * 262144 + qt * 4096;
  const unsigned short* khp = KF + (size_t)(b * 4 + kh) * 262144;
  const unsigned short* vhp = VF + (size_t)(b * 4 + kh) * 262144;

  short8 qf[8];
  #pragma unroll
  for (int s = 0; s < 8; s++)
    qf[s] = *(const short8*)(qh + s * 512 + lane * 8);

  float m_r = -3.0e38f, l_r = 0.f;
  f32x16 oacc[4];
  #pragma unroll
  for (int dt = 0; dt < 4; dt++)
    #pragma unroll
    for (int r = 0; r < 16; r++) oacc[dt][r] = 0.f;

  for (int kt = 0; kt < nw; kt++) {
    const int kv0 = kt * 64;
    // QK^T: S^T[kv][q], two 32x32 tiles; K A-fragments are lane-contiguous 1KB bursts
    f32x16 sc[2];
    {
      short8 kf0[8];
      #pragma unroll
      for (int s = 0; s < 8; s++)
        kf0[s] = *(const short8*)(khp + (size_t)(2 * kt) * 4096 + s * 512 + lane * 8);
      #pragma unroll
      for (int r = 0; r < 16; r++) sc[0][r] = 0.f;
      #pragma unroll
      for (int s = 0; s < 8; s++)
        sc[0] = __builtin_amdgcn_mfma_f32_32x32x16_bf16(kf0[s], qf[s], sc[0], 0, 0, 0);
    }
    {
      short8 kf1[8];
      #pragma unroll
      for (int s = 0; s < 8; s++)
        kf1[s] = *(const short8*)(khp + (size_t)(2 * kt + 1) * 4096 + s * 512 + lane * 8);
      #pragma unroll
      for (int r = 0; r < 16; r++) sc[1][r] = 0.f;
      #pragma unroll
      for (int s = 0; s < 8; s++)
        sc[1] = __builtin_amdgcn_mfma_f32_32x32x16_bf16(kf1[s], qf[s], sc[1], 0, 0, 0);
    }
    // issue V loads now; latency hides under softmax VALU
    short8 vf[4][4];
    #pragma unroll
    for (int dt = 0; dt < 4; dt++)
      #pragma unroll
      for (int ks = 0; ks < 4; ks++)
        vf[dt][ks] = *(const short8*)(vhp + (size_t)kt * 8192 + (dt * 4 + ks) * 512 + lane * 8);

    // causal mask (final tile only): C row = kv, col = q
    if (kv0 + 63 > qw) {
      #pragma unroll
      for (int ct = 0; ct < 2; ct++)
        #pragma unroll
        for (int r = 0; r < 16; r++) {
          int kg = kv0 + ct * 32 + (r & 3) + 8 * (r >> 2) + 4 * hf;
          if (kg > qw + l31) sc[ct][r] = -3.0e38f;
        }
    }
    // row max
    float mx[16];
    #pragma unroll
    for (int r = 0; r < 16; r++) mx[r] = fmaxf(sc[0][r], sc[1][r]);
    #pragma unroll
    for (int s2 = 8; s2 >= 1; s2 >>= 1)
      #pragma unroll
      for (int i = 0; i < 8; i++) if (i < s2) mx[i] = fmaxf(mx[i], mx[i + s2]);
    float tm = fmaxf(mx[0], __shfl_xor(mx[0], 32));
    // defer-max rescale (exp2 domain, P <= 2^8)
    if (__any(tm > m_r + 8.0f)) {
      float mn = fmaxf(m_r, tm);
      float al = __builtin_amdgcn_exp2f(m_r - mn);
      m_r = mn;
      l_r *= al;
      #pragma unroll
      for (int r = 0; r < 16; r++) {
        float alr = bcast32(al, (r & 3) + 8 * (r >> 2) + 4 * hf);
        #pragma unroll
        for (int dt = 0; dt < 4; dt++) oacc[dt][r] *= alr;
      }
    }
    #pragma unroll
    for (int ct = 0; ct < 2; ct++)
      #pragma unroll
      for (int r = 0; r < 16; r++) sc[ct][r] = __builtin_amdgcn_exp2f(sc[ct][r] - m_r);
    float sm[16];
    #pragma unroll
    for (int r = 0; r < 16; r++) sm[r] = sc[0][r] + sc[1][r];
    #pragma unroll
    for (int s2 = 8; s2 >= 1; s2 >>= 1)
      #pragma unroll
      for (int i = 0; i < 8; i++) if (i < s2) sm[i] += sm[i + s2];
    l_r += sm[0];                    // partial (own 32 kv); combined in epilogue

    // repack P -> A-fragments: 16 cvt_pk + 8 permlane32_swap
    short8 pa[4];
    #pragma unroll
    for (int ks = 0; ks < 4; ks++) {
      const int ct = ks >> 1, kb = (ks & 1) * 8;
      unsigned int A0 = cvtpk_bf16(sc[ct][kb + 0], sc[ct][kb + 1]);
      unsigned int A1 = cvtpk_bf16(sc[ct][kb + 2], sc[ct][kb + 3]);
      unsigned int B0 = cvtpk_bf16(sc[ct][kb + 4], sc[ct][kb + 5]);
      unsigned int B1 = cvtpk_bf16(sc[ct][kb + 6], sc[ct][kb + 7]);
      plswap32(A0, B0);
      plswap32(A1, B1);
      union { unsigned int wds[4]; short8 s8; } u;
      u.wds[0] = A0; u.wds[1] = A1; u.wds[2] = B0; u.wds[3] = B1;
      pa[ks] = u.s8;
    }
    // PV: O[32q x 128d] += P[32x64] * V[64x128]
    #pragma unroll
    for (int dt = 0; dt < 4; dt++)
      #pragma unroll
      for (int ks = 0; ks < 4; ks++)
        oacc[dt] = __builtin_amdgcn_mfma_f32_32x32x16_bf16(pa[ks], vf[dt][ks], oacc[dt], 0, 0, 0);
  }
  // epilogue: combine l halves, broadcast 1/l per row, write O[b][q][h*128 + d]
  float invl = 1.0f / (l_r + __shfl_xor(l_r, 32));
  #pragma unroll
  for (int r = 0; r < 16; r++) {
    int rloc = (r & 3) + 8 * (r >> 2) + 4 * hf;
    float inv = bcast32(invl, rloc);
    int qg = qw + rloc;
    unsigned short* orow = O + ((size_t)(b * 2048 + qg)) * 2048 + h * 128;
    #pragma unroll
    for (int dt = 0; dt < 4; dt++)
      orow[dt * 32 + l31] = f2bf(oacc[dt][r] * inv);
  }
}

// ---------------- launch ----------------
extern "C" void kernel_launch(void* const* d_in, const int* in_sizes, int n_in,
                              void* d_out, int out_size, void* d_ws, size_t ws_size,
                              hipStream_t stream) {
  (void)in_sizes; (void)n_in; (void)out_size; (void)ws_size;
  const float* x  = (const float*)d_in[0];
  const float* Wq = (const float*)d_in[1];
  const float* bq = (const float*)d_in[2];
  const float* Wk = (const float*)d_in[3];
  const float* bk = (const float*)d_in[4];
  const float* Wv = (const float*)d_in[5];
  const float* bv = (const float*)d_in[6];
  const float* Wo = (const float*)d_in[7];
  const float* bo = (const float*)d_in[8];
  const int*   sp = (const int*)d_in[9];

  char* ws = (char*)d_ws;
  unsigned short* xb    = (unsigned short*)ws;                // 16,777,216 B (reused as Obuf)
  unsigned short* Wqkvt = (unsigned short*)(ws + 16777216);   // 12,582,912
  unsigned short* Wot   = (unsigned short*)(ws + 29360128);   //  8,388,608
  unsigned short* QKVb  = (unsigned short*)(ws + 37748736);   // 25,165,824 (bf16 [4096][3072])
  float* cost           = (float*)(ws + 62914560);            //    262,144
  float* sint           = (float*)(ws + 63176704);            //    262,144
  float* bcat           = (float*)(ws + 63438848);            //     12,288

  unsigned short* Obuf = xb;  // xb dead after GEMM1
  unsigned short* QFr = (unsigned short*)d_out;
  unsigned short* KFr = (unsigned short*)((char*)d_out + 16777216);
  unsigned short* VFr = (unsigned short*)((char*)d_out + 20971520);

  mk_tables<<<256, 256, 0, stream>>>(cost, sint);
  bias_cat_k<<<12, 256, 0, stream>>>(bq, bk, bv, bcat);
  convx<<<4096, 256, 0, stream>>>(x, xb);
  transw<<<dim3(64, 64), 256, 0, stream>>>(Wq, Wqkvt, 2048);
  transw<<<dim3(16, 64), 256, 0, stream>>>(Wk, Wqkvt + (size_t)2048 * 2048, 512);
  transw<<<dim3(16, 64), 256, 0, stream>>>(Wv, Wqkvt + (size_t)2560 * 2048, 512);
  transw<<<dim3(64, 64), 256, 0, stream>>>(Wo, Wot, 2048);
  gemm_bt<true><<<dim3(24, 32), 256, 0, stream>>>(xb, Wqkvt, bcat, QKVb, 4096, 3072, 2048);
  // Q scale = (1/sqrt(128)) * log2(e) so softmax can use exp2 directly
  rope_scatter<16><<<16384, 256, 0, stream>>>(QKVb, cost, sint, sp, QFr, 0, 0.12751743f);
  rope_scatter<4><<<4096, 256, 0, stream>>>(QKVb, cost, sint, sp, KFr, 2048, 1.0f);
  vtrans<<<dim3(32, 8), 256, 0, stream>>>(QKVb, VFr);
  attn_kernel<<<dim3(256), 512, 0, stream>>>(QFr, KFr, VFr, Obuf);
  gemm_bt<false><<<dim3(16, 32), 256, 0, stream>>>(Obuf, Wot, bo, (float*)d_out, 4096, 2048, 2048);
}